// Round 2
// baseline (1356.804 us; speedup 1.0000x reference)
//
#include <hip/hip_runtime.h>

#define NN   100000
#define NE   3200000
#define INF_ 512
#define HIDF 64
#define OUTF 16

// ---------------------------------------------------------------- degree ----
__global__ __launch_bounds__(256) void k_deg_init(int* __restrict__ deg) {
    int i = blockIdx.x * 256 + threadIdx.x;
    if (i < NN) deg[i] = 1;               // self-loop contributes 1
}

__global__ __launch_bounds__(256) void k_deg_count(const int* __restrict__ dst,
                                                   int* __restrict__ deg) {
    int e = blockIdx.x * 256 + threadIdx.x;
    if (e < NE) atomicAdd(&deg[dst[e]], 1);
}

__global__ __launch_bounds__(256) void k_dinv(const int* __restrict__ deg,
                                              float* __restrict__ dinv) {
    int i = blockIdx.x * 256 + threadIdx.x;
    if (i < NN) dinv[i] = rsqrtf((float)deg[i]);   // deg >= 1 always
}

// ---------------------------------------------------------------- GEMM1 -----
// h1p[n][64] = x[n][:] @ W1.  One wave per 8 nodes; lane = output feature.
// x-row loads are wave-uniform -> scalar loads broadcast to all 64 lanes;
// W1[k][f] loads are lane-contiguous (256B coalesced, L2-hot).
__global__ __launch_bounds__(256) void k_gemm1(const float* __restrict__ x,
                                               const float* __restrict__ W1,
                                               float* __restrict__ h1p) {
    int tid  = blockIdx.x * 256 + threadIdx.x;
    int f    = tid & 63;
    int wave = __builtin_amdgcn_readfirstlane(tid >> 6);   // 0..12499
    long long n0 = (long long)wave * 8;
    const float* xr = x + n0 * INF_;

    float acc[8];
#pragma unroll
    for (int j = 0; j < 8; ++j) acc[j] = 0.f;

#pragma unroll 4
    for (int k = 0; k < INF_; ++k) {
        float w = W1[k * HIDF + f];
#pragma unroll
        for (int j = 0; j < 8; ++j)
            acc[j] = fmaf(xr[(size_t)j * INF_ + k], w, acc[j]);
    }
#pragma unroll
    for (int j = 0; j < 8; ++j)
        h1p[(n0 + j) * HIDF + f] = acc[j];
}

// -------------------------------------------------------------- scatter1 ---
// Wave per edge, lane = feature. Gather h1p[src] (256B coalesced, L3-hot),
// atomicAdd into agg1[dst].
__global__ __launch_bounds__(256) void k_scatter1(const int* __restrict__ src,
                                                  const int* __restrict__ dst,
                                                  const float* __restrict__ dinv,
                                                  const float* __restrict__ h1p,
                                                  float* __restrict__ agg1) {
    int lane = threadIdx.x & 63;
    int wid  = __builtin_amdgcn_readfirstlane((blockIdx.x * 256 + threadIdx.x) >> 6);
    int nw   = gridDim.x << 2;                 // waves in grid
    for (int e = wid; e < NE; e += nw) {
        int s = src[e];
        int d = dst[e];
        float w = dinv[s] * dinv[d];
        float v = h1p[(size_t)s * HIDF + lane] * w;
        atomicAdd(&agg1[(size_t)d * HIDF + lane], v);
    }
}

// ------------------------------------------- fused self+bias+ReLU + GEMM2 --
// hid = relu(agg1 + h1p*dinv^2 + b1);  h2 = hid @ W2.  Thread per node.
__global__ __launch_bounds__(256) void k_gemm2(const float* __restrict__ agg1,
                                               const float* __restrict__ h1p,
                                               const float* __restrict__ dinv,
                                               const float* __restrict__ b1,
                                               const float* __restrict__ W2,
                                               float* __restrict__ h2) {
    int n = blockIdx.x * 256 + threadIdx.x;
    if (n >= NN) return;
    float di = dinv[n], d2 = di * di;
    const float* a = agg1 + (size_t)n * HIDF;
    const float* p = h1p  + (size_t)n * HIDF;

    float acc[OUTF];
#pragma unroll
    for (int f = 0; f < OUTF; ++f) acc[f] = 0.f;

#pragma unroll 4
    for (int k = 0; k < HIDF; ++k) {
        float hv = fmaxf(a[k] + p[k] * d2 + b1[k], 0.f);
#pragma unroll
        for (int f = 0; f < OUTF; ++f)
            acc[f] = fmaf(hv, W2[k * OUTF + f], acc[f]);
    }
#pragma unroll
    for (int f = 0; f < OUTF; ++f)
        h2[(size_t)n * OUTF + f] = acc[f];
}

// -------------------------------------------------------------- scatter2 ---
// Thread per (edge, feature). 16 consecutive threads share one edge.
__global__ __launch_bounds__(256) void k_scatter2(const int* __restrict__ src,
                                                  const int* __restrict__ dst,
                                                  const float* __restrict__ dinv,
                                                  const float* __restrict__ h2,
                                                  float* __restrict__ agg2) {
    long long t = (long long)blockIdx.x * 256 + threadIdx.x;
    if (t >= (long long)NE * OUTF) return;
    int e = (int)(t >> 4);
    int f = (int)(t & 15);
    int s = src[e];
    int d = dst[e];
    float w = dinv[s] * dinv[d];
    atomicAdd(&agg2[(size_t)d * OUTF + f], h2[(size_t)s * OUTF + f] * w);
}

// ------------------------------------------ fused self+bias+log_softmax ----
__global__ __launch_bounds__(256) void k_out(const float* __restrict__ agg2,
                                             const float* __restrict__ h2,
                                             const float* __restrict__ dinv,
                                             const float* __restrict__ b2,
                                             float* __restrict__ out) {
    int n = blockIdx.x * 256 + threadIdx.x;
    if (n >= NN) return;
    float di = dinv[n], d2 = di * di;
    float v[OUTF];
#pragma unroll
    for (int f = 0; f < OUTF; ++f)
        v[f] = agg2[(size_t)n * OUTF + f] + h2[(size_t)n * OUTF + f] * d2 + b2[f];
    float m = v[0];
#pragma unroll
    for (int f = 1; f < OUTF; ++f) m = fmaxf(m, v[f]);
    float s = 0.f;
#pragma unroll
    for (int f = 0; f < OUTF; ++f) s += __expf(v[f] - m);
    float ls = m + __logf(s);
#pragma unroll
    for (int f = 0; f < OUTF; ++f)
        out[(size_t)n * OUTF + f] = v[f] - ls;
}

// ----------------------------------------------------------------- launch --
extern "C" void kernel_launch(void* const* d_in, const int* in_sizes, int n_in,
                              void* d_out, int out_size, void* d_ws, size_t ws_size,
                              hipStream_t stream) {
    const float* x  = (const float*)d_in[0];
    const int*   ei = (const int*)d_in[1];    // [2][NE], delivered as int32
    const float* W1 = (const float*)d_in[2];
    const float* b1 = (const float*)d_in[3];
    const float* W2 = (const float*)d_in[4];
    const float* b2 = (const float*)d_in[5];
    float*       out = (float*)d_out;

    char*  ws = (char*)d_ws;
    size_t o  = 0;
    auto alloc = [&](size_t bytes) {
        void* p = ws + o;
        o = (o + bytes + 1023) & ~(size_t)1023;
        return p;
    };
    int*   degcnt = (int*)  alloc((size_t)NN * 4);
    float* dinv   = (float*)alloc((size_t)NN * 4);
    float* h1p    = (float*)alloc((size_t)NN * HIDF * 4);
    float* agg1   = (float*)alloc((size_t)NN * HIDF * 4);
    float* h2     = (float*)alloc((size_t)NN * OUTF * 4);
    float* agg2   = (float*)alloc((size_t)NN * OUTF * 4);
    if (o > ws_size) return;   // insufficient scratch -> visible failure

    const int* esrc = ei;
    const int* edst = ei + NE;

    hipMemsetAsync(agg1, 0, (size_t)NN * HIDF * 4, stream);
    hipMemsetAsync(agg2, 0, (size_t)NN * OUTF * 4, stream);

    k_deg_init <<<(NN + 255) / 256, 256, 0, stream>>>(degcnt);
    k_deg_count<<<(NE + 255) / 256, 256, 0, stream>>>(edst, degcnt);
    k_dinv     <<<(NN + 255) / 256, 256, 0, stream>>>(degcnt, dinv);

    k_gemm1    <<<(NN / 8) * 64 / 256, 256, 0, stream>>>(x, W1, h1p);   // 3125 blocks
    k_scatter1 <<<2048, 256, 0, stream>>>(esrc, edst, dinv, h1p, agg1);
    k_gemm2    <<<(NN + 255) / 256, 256, 0, stream>>>(agg1, h1p, dinv, b1, W2, h2);
    k_scatter2 <<<(int)(((long long)NE * OUTF + 255) / 256), 256, 0, stream>>>(esrc, edst, dinv, h2, agg2);
    k_out      <<<(NN + 255) / 256, 256, 0, stream>>>(agg2, h2, dinv, b2, out);
}

// Round 3
// 930.958 us; speedup vs baseline: 1.4574x; 1.4574x over previous
//
#include <hip/hip_runtime.h>

#define NN   100000
#define NE   3200000
#define INF_ 512
#define HIDF 64
#define OUTF 16
#define NB_SCAN ((NN + 1023) / 1024)   // 98 blocks of 1024

// ---------------------------------------------------------------- degree ----
__global__ __launch_bounds__(256) void k_deg_count(const int* __restrict__ dst,
                                                   int* __restrict__ cnt) {
    int e = blockIdx.x * 256 + threadIdx.x;
    if (e < NE) atomicAdd(&cnt[dst[e]], 1);
}

__global__ __launch_bounds__(256) void k_dinv(const int* __restrict__ cnt,
                                              float* __restrict__ dinv) {
    int i = blockIdx.x * 256 + threadIdx.x;
    if (i < NN) dinv[i] = rsqrtf((float)(cnt[i] + 1));   // +1 self-loop
}

// ------------------------------------------------------------------ scan ----
// Exclusive prefix sum of cnt[NN] -> rs[NN+1]; 2-level (1024/block).
__global__ __launch_bounds__(256) void k_scan1(const int* __restrict__ cnt,
                                               int* __restrict__ rs,
                                               int* __restrict__ bsum) {
    __shared__ int lds[256];
    int b = blockIdx.x, t = threadIdx.x;
    int base = b * 1024 + t * 4;
    int c[4];
#pragma unroll
    for (int i = 0; i < 4; ++i) { int idx = base + i; c[i] = idx < NN ? cnt[idx] : 0; }
    int tsum = c[0] + c[1] + c[2] + c[3];
    lds[t] = tsum;
    __syncthreads();
    for (int off = 1; off < 256; off <<= 1) {
        int v = lds[t];
        int a = (t >= off) ? lds[t - off] : 0;
        __syncthreads();
        lds[t] = v + a;
        __syncthreads();
    }
    int pre = (t == 0) ? 0 : lds[t - 1];
    if (t == 255) bsum[b] = lds[255];
    int run = pre;
#pragma unroll
    for (int i = 0; i < 4; ++i) { int idx = base + i; if (idx < NN) rs[idx] = run; run += c[i]; }
}

__global__ __launch_bounds__(128) void k_scan2(int* __restrict__ bsum,
                                               int* __restrict__ boff) {
    __shared__ int lds[128];
    int t = threadIdx.x;
    lds[t] = (t < NB_SCAN) ? bsum[t] : 0;
    __syncthreads();
    for (int off = 1; off < 128; off <<= 1) {
        int v = lds[t];
        int a = (t >= off) ? lds[t - off] : 0;
        __syncthreads();
        lds[t] = v + a;
        __syncthreads();
    }
    if (t < NB_SCAN) boff[t] = (t == 0) ? 0 : lds[t - 1];
}

__global__ __launch_bounds__(256) void k_scan3(int* __restrict__ rs,
                                               const int* __restrict__ boff,
                                               int* __restrict__ cursor) {
    int i = blockIdx.x * 256 + threadIdx.x;
    if (i < NN) {
        int v = rs[i] + boff[i >> 10];
        rs[i] = v;
        cursor[i] = v;
    }
    if (i == 0) rs[NN] = NE;
}

// ------------------------------------------------------------------ fill ----
__global__ __launch_bounds__(256) void k_fill(const int* __restrict__ src,
                                              const int* __restrict__ dst,
                                              int* __restrict__ cursor,
                                              int* __restrict__ csr) {
    int e = blockIdx.x * 256 + threadIdx.x;
    if (e < NE) {
        int pos = atomicAdd(&cursor[dst[e]], 1);
        csr[pos] = src[e];
    }
}

// ---------------------------------------------------------------- GEMM1 -----
// h1p[n][64] = x[n][:] @ W1.  One wave per 8 nodes; lane = output feature.
__global__ __launch_bounds__(256) void k_gemm1(const float* __restrict__ x,
                                               const float* __restrict__ W1,
                                               float* __restrict__ h1p) {
    int tid  = blockIdx.x * 256 + threadIdx.x;
    int f    = tid & 63;
    int wave = __builtin_amdgcn_readfirstlane(tid >> 6);   // 0..12499
    long long n0 = (long long)wave * 8;
    const float* xr = x + n0 * INF_;

    float acc[8];
#pragma unroll
    for (int j = 0; j < 8; ++j) acc[j] = 0.f;

#pragma unroll 4
    for (int k = 0; k < INF_; ++k) {
        float w = W1[k * HIDF + f];
#pragma unroll
        for (int j = 0; j < 8; ++j)
            acc[j] = fmaf(xr[(size_t)j * INF_ + k], w, acc[j]);
    }
#pragma unroll
    for (int j = 0; j < 8; ++j)
        h1p[(n0 + j) * HIDF + f] = acc[j];
}

// --------------------------------------------------- layer1 aggregate ------
// One wave per dst node, lane = feature (64). No atomics.
// hid[n][f] = relu( dinv[n]*( sum_in dinv[s]*h1p[s][f] + dinv[n]*h1p[n][f] ) + b1[f] )
__global__ __launch_bounds__(256) void k_hid(const int* __restrict__ rs,
                                             const int* __restrict__ csr,
                                             const float* __restrict__ dinv,
                                             const float* __restrict__ h1p,
                                             const float* __restrict__ b1,
                                             float* __restrict__ hid) {
    int f = threadIdx.x & 63;
    int n = (blockIdx.x * 256 + threadIdx.x) >> 6;   // one wave per node
    if (n >= NN) return;
    int row = rs[n], end = rs[n + 1];
    float dn = dinv[n];
    float acc = dn * h1p[n * HIDF + f];              // self-loop (inner dinv[n])

    int j = row;
    for (; j + 4 <= end; j += 4) {
        int s0 = csr[j], s1 = csr[j + 1], s2 = csr[j + 2], s3 = csr[j + 3];
        float w0 = dinv[s0], w1 = dinv[s1], w2 = dinv[s2], w3 = dinv[s3];
        acc = fmaf(h1p[s0 * HIDF + f], w0, acc);
        acc = fmaf(h1p[s1 * HIDF + f], w1, acc);
        acc = fmaf(h1p[s2 * HIDF + f], w2, acc);
        acc = fmaf(h1p[s3 * HIDF + f], w3, acc);
    }
    for (; j < end; ++j) {
        int s = csr[j];
        acc = fmaf(h1p[s * HIDF + f], dinv[s], acc);
    }
    hid[n * HIDF + f] = fmaxf(fmaf(dn, acc, b1[f]), 0.f);
}

// ---------------------------------------------------------------- GEMM2 -----
// h2[n][16] = hid[n][:] @ W2.  Thread per node.
__global__ __launch_bounds__(256) void k_gemm2(const float* __restrict__ hid,
                                               const float* __restrict__ W2,
                                               float* __restrict__ h2) {
    int n = blockIdx.x * 256 + threadIdx.x;
    if (n >= NN) return;
    const float* p = hid + (size_t)n * HIDF;
    float acc[OUTF];
#pragma unroll
    for (int f = 0; f < OUTF; ++f) acc[f] = 0.f;
#pragma unroll 4
    for (int k = 0; k < HIDF; ++k) {
        float hv = p[k];
#pragma unroll
        for (int f = 0; f < OUTF; ++f)
            acc[f] = fmaf(hv, W2[k * OUTF + f], acc[f]);
    }
#pragma unroll
    for (int f = 0; f < OUTF; ++f)
        h2[(size_t)n * OUTF + f] = acc[f];
}

// --------------------------- layer2 aggregate + bias + log_softmax ---------
// 16 threads per node (lane group). No atomics; fused epilogue.
__global__ __launch_bounds__(256) void k_out2(const int* __restrict__ rs,
                                              const int* __restrict__ csr,
                                              const float* __restrict__ dinv,
                                              const float* __restrict__ h2,
                                              const float* __restrict__ b2,
                                              float* __restrict__ out) {
    int t = blockIdx.x * 256 + threadIdx.x;
    int n = t >> 4;
    int f = t & 15;
    if (n >= NN) return;
    int row = rs[n], end = rs[n + 1];
    float dn = dinv[n];
    float acc = dn * h2[n * OUTF + f];               // self-loop

    int j = row;
    for (; j + 2 <= end; j += 2) {
        int s0 = csr[j], s1 = csr[j + 1];
        acc = fmaf(h2[s0 * OUTF + f], dinv[s0], acc);
        acc = fmaf(h2[s1 * OUTF + f], dinv[s1], acc);
    }
    for (; j < end; ++j) {
        int s = csr[j];
        acc = fmaf(h2[s * OUTF + f], dinv[s], acc);
    }
    float v = fmaf(dn, acc, b2[f]);

    // log_softmax across the 16-lane group
    float m = v;
#pragma unroll
    for (int mask = 1; mask < 16; mask <<= 1)
        m = fmaxf(m, __shfl_xor(m, mask, 16));
    float ex = __expf(v - m);
    float s  = ex;
#pragma unroll
    for (int mask = 1; mask < 16; mask <<= 1)
        s += __shfl_xor(s, mask, 16);
    out[(size_t)n * OUTF + f] = v - (m + __logf(s));
}

// ----------------------------------------------------------------- launch --
extern "C" void kernel_launch(void* const* d_in, const int* in_sizes, int n_in,
                              void* d_out, int out_size, void* d_ws, size_t ws_size,
                              hipStream_t stream) {
    const float* x  = (const float*)d_in[0];
    const int*   ei = (const int*)d_in[1];    // [2][NE], delivered as int32
    const float* W1 = (const float*)d_in[2];
    const float* b1 = (const float*)d_in[3];
    const float* W2 = (const float*)d_in[4];
    const float* b2 = (const float*)d_in[5];
    float*       out = (float*)d_out;

    char*  ws = (char*)d_ws;
    size_t o  = 0;
    auto alloc = [&](size_t bytes) {
        void* p = ws + o;
        o = (o + bytes + 1023) & ~(size_t)1023;
        return p;
    };
    int*   cnt    = (int*)  alloc((size_t)NN * 4);
    int*   rs     = (int*)  alloc((size_t)(NN + 1) * 4);
    int*   cursor = (int*)  alloc((size_t)NN * 4);
    int*   bsum   = (int*)  alloc((size_t)NB_SCAN * 4);
    int*   boff   = (int*)  alloc((size_t)NB_SCAN * 4);
    int*   csr    = (int*)  alloc((size_t)NE * 4);
    float* dinv   = (float*)alloc((size_t)NN * 4);
    float* h1p    = (float*)alloc((size_t)NN * HIDF * 4);
    float* hid    = (float*)alloc((size_t)NN * HIDF * 4);
    float* h2     = (float*)alloc((size_t)NN * OUTF * 4);
    if (o > ws_size) return;   // insufficient scratch -> visible failure

    const int* esrc = ei;
    const int* edst = ei + NE;

    hipMemsetAsync(cnt, 0, (size_t)NN * 4, stream);

    k_deg_count<<<(NE + 255) / 256, 256, 0, stream>>>(edst, cnt);
    k_dinv     <<<(NN + 255) / 256, 256, 0, stream>>>(cnt, dinv);
    k_scan1    <<<NB_SCAN, 256, 0, stream>>>(cnt, rs, bsum);
    k_scan2    <<<1, 128, 0, stream>>>(bsum, boff);
    k_scan3    <<<(NN + 255) / 256, 256, 0, stream>>>(rs, boff, cursor);
    k_fill     <<<(NE + 255) / 256, 256, 0, stream>>>(esrc, edst, cursor, csr);

    k_gemm1    <<<(NN / 8) * 64 / 256, 256, 0, stream>>>(x, W1, h1p);   // 3125 blocks
    k_hid      <<<(NN * 64 + 255) / 256, 256, 0, stream>>>(rs, csr, dinv, h1p, b1, hid);
    k_gemm2    <<<(NN + 255) / 256, 256, 0, stream>>>(hid, W2, h2);
    k_out2     <<<(NN * OUTF + 255) / 256, 256, 0, stream>>>(rs, csr, dinv, h2, b2, out);
}

// Round 4
// 677.913 us; speedup vs baseline: 2.0014x; 1.3733x over previous
//
#include <hip/hip_runtime.h>

#define NN   100000
#define NE   3200000
#define INF_ 512
#define HIDF 64
#define OUTF 16
#define NB_SCAN ((NN + 1023) / 1024)   // 98 blocks of 1024

// ---------------------------------------------------------------- degree ----
__global__ __launch_bounds__(256) void k_deg_count(const int* __restrict__ dst,
                                                   int* __restrict__ cnt) {
    int e = blockIdx.x * 256 + threadIdx.x;
    if (e < NE) atomicAdd(&cnt[dst[e]], 1);
}

__global__ __launch_bounds__(256) void k_dinv(const int* __restrict__ cnt,
                                              float* __restrict__ dinv) {
    int i = blockIdx.x * 256 + threadIdx.x;
    if (i < NN) dinv[i] = rsqrtf((float)(cnt[i] + 1));   // +1 self-loop
}

// ------------------------------------------------------------------ scan ----
__global__ __launch_bounds__(256) void k_scan1(const int* __restrict__ cnt,
                                               int* __restrict__ rs,
                                               int* __restrict__ bsum) {
    __shared__ int lds[256];
    int b = blockIdx.x, t = threadIdx.x;
    int base = b * 1024 + t * 4;
    int c[4];
#pragma unroll
    for (int i = 0; i < 4; ++i) { int idx = base + i; c[i] = idx < NN ? cnt[idx] : 0; }
    int tsum = c[0] + c[1] + c[2] + c[3];
    lds[t] = tsum;
    __syncthreads();
    for (int off = 1; off < 256; off <<= 1) {
        int v = lds[t];
        int a = (t >= off) ? lds[t - off] : 0;
        __syncthreads();
        lds[t] = v + a;
        __syncthreads();
    }
    int pre = (t == 0) ? 0 : lds[t - 1];
    if (t == 255) bsum[b] = lds[255];
    int run = pre;
#pragma unroll
    for (int i = 0; i < 4; ++i) { int idx = base + i; if (idx < NN) rs[idx] = run; run += c[i]; }
}

__global__ __launch_bounds__(128) void k_scan2(int* __restrict__ bsum,
                                               int* __restrict__ boff) {
    __shared__ int lds[128];
    int t = threadIdx.x;
    lds[t] = (t < NB_SCAN) ? bsum[t] : 0;
    __syncthreads();
    for (int off = 1; off < 128; off <<= 1) {
        int v = lds[t];
        int a = (t >= off) ? lds[t - off] : 0;
        __syncthreads();
        lds[t] = v + a;
        __syncthreads();
    }
    if (t < NB_SCAN) boff[t] = (t == 0) ? 0 : lds[t - 1];
}

__global__ __launch_bounds__(256) void k_scan3(int* __restrict__ rs,
                                               const int* __restrict__ boff,
                                               int* __restrict__ cursor) {
    int i = blockIdx.x * 256 + threadIdx.x;
    if (i < NN) {
        int v = rs[i] + boff[i >> 10];
        rs[i] = v;
        cursor[i] = v;
    }
    if (i == 0) rs[NN] = NE;
}

// ------------------------------------------------------------------ fill ----
__global__ __launch_bounds__(256) void k_fill(const int* __restrict__ src,
                                              const int* __restrict__ dst,
                                              int* __restrict__ cursor,
                                              int* __restrict__ csr) {
    int e = blockIdx.x * 256 + threadIdx.x;
    if (e < NE) {
        int pos = atomicAdd(&cursor[dst[e]], 1);
        csr[pos] = src[e];
    }
}

// ---------------------------------------------------------------- GEMM1 -----
// h1p[0:NN][0:64] = x @ W1, LDS-tiled. Tile: M=128 nodes, N=64 (full), KC=32.
// 256 threads; each computes 4 nodes x 8 feats. x staged TRANSPOSED so the
// compute loop does consecutive-chunk ds_read_b128 (conflict-free).
#define MT 128
#define KC 32
#define XT_STR 132   // words: 128 + 4 pad; 132*4 B is 16B-aligned per k-row
#define WT_STR 68    // words: 64 + 4 pad

__global__ __launch_bounds__(256) void k_gemm1(const float* __restrict__ x,
                                               const float* __restrict__ W1,
                                               float* __restrict__ h1p) {
    __shared__ float xt[KC * XT_STR];   // 16.9 KB
    __shared__ float wt[KC * WT_STR];   // 8.7 KB
    int t = threadIdx.x;
    int mbase = blockIdx.x * MT;

    int n0 = (t & 31) * 4;   // node offset within tile
    int f0 = (t >> 5) * 8;   // feat offset

    int lr = t >> 3;          // x-stage: row 0..31 (+32*i)
    int lc = (t & 7) * 4;     // x-stage: col (k) 0..28

    float acc[4][8];
#pragma unroll
    for (int a = 0; a < 4; ++a)
#pragma unroll
        for (int b = 0; b < 8; ++b) acc[a][b] = 0.f;

    for (int kc = 0; kc < INF_; kc += KC) {
        // ---- stage x[mbase:+128][kc:+32] -> xt[k][m] (transposed)
#pragma unroll
        for (int i = 0; i < 4; ++i) {
            int row = mbase + lr + i * 32;
            int rowc = row < NN ? row : NN - 1;
            float4 v = *(const float4*)&x[(size_t)rowc * INF_ + kc + lc];
            int m = lr + i * 32;
            xt[(lc + 0) * XT_STR + m] = v.x;
            xt[(lc + 1) * XT_STR + m] = v.y;
            xt[(lc + 2) * XT_STR + m] = v.z;
            xt[(lc + 3) * XT_STR + m] = v.w;
        }
        // ---- stage W1[kc:+32][0:64] -> wt[k][f]
#pragma unroll
        for (int i = 0; i < 2; ++i) {
            int idx = t + 256 * i;          // 0..511 over [32][16] float4s
            int k  = idx >> 4;
            int c4 = (idx & 15) * 4;
            float4 v = *(const float4*)&W1[(size_t)(kc + k) * HIDF + c4];
            *(float4*)&wt[k * WT_STR + c4] = v;
        }
        __syncthreads();

        // ---- compute
#pragma unroll 8
        for (int k = 0; k < KC; ++k) {
            float4 xv = *(const float4*)&xt[k * XT_STR + n0];
            float4 wa = *(const float4*)&wt[k * WT_STR + f0];
            float4 wb = *(const float4*)&wt[k * WT_STR + f0 + 4];
            float xs[4] = {xv.x, xv.y, xv.z, xv.w};
            float ws[8] = {wa.x, wa.y, wa.z, wa.w, wb.x, wb.y, wb.z, wb.w};
#pragma unroll
            for (int a = 0; a < 4; ++a)
#pragma unroll
                for (int b = 0; b < 8; ++b)
                    acc[a][b] = fmaf(xs[a], ws[b], acc[a][b]);
        }
        __syncthreads();
    }

    // ---- store 4 nodes x 8 feats
#pragma unroll
    for (int a = 0; a < 4; ++a) {
        int n = mbase + n0 + a;
        if (n < NN) {
            *(float4*)&h1p[(size_t)n * HIDF + f0]     = make_float4(acc[a][0], acc[a][1], acc[a][2], acc[a][3]);
            *(float4*)&h1p[(size_t)n * HIDF + f0 + 4] = make_float4(acc[a][4], acc[a][5], acc[a][6], acc[a][7]);
        }
    }
}

// --------------------------------------------------- layer1 aggregate ------
// One wave per dst node, lane = feature (64). No atomics.
__global__ __launch_bounds__(256) void k_hid(const int* __restrict__ rs,
                                             const int* __restrict__ csr,
                                             const float* __restrict__ dinv,
                                             const float* __restrict__ h1p,
                                             const float* __restrict__ b1,
                                             float* __restrict__ hid) {
    int f = threadIdx.x & 63;
    int n = (blockIdx.x * 256 + threadIdx.x) >> 6;   // one wave per node
    if (n >= NN) return;
    int row = rs[n], end = rs[n + 1];
    float dn = dinv[n];
    float acc = dn * h1p[n * HIDF + f];              // self-loop

    int j = row;
    for (; j + 4 <= end; j += 4) {
        int s0 = csr[j], s1 = csr[j + 1], s2 = csr[j + 2], s3 = csr[j + 3];
        float w0 = dinv[s0], w1 = dinv[s1], w2 = dinv[s2], w3 = dinv[s3];
        acc = fmaf(h1p[s0 * HIDF + f], w0, acc);
        acc = fmaf(h1p[s1 * HIDF + f], w1, acc);
        acc = fmaf(h1p[s2 * HIDF + f], w2, acc);
        acc = fmaf(h1p[s3 * HIDF + f], w3, acc);
    }
    for (; j < end; ++j) {
        int s = csr[j];
        acc = fmaf(h1p[s * HIDF + f], dinv[s], acc);
    }
    hid[n * HIDF + f] = fmaxf(fmaf(dn, acc, b1[f]), 0.f);
}

// ---------------------------------------------------------------- GEMM2 -----
__global__ __launch_bounds__(256) void k_gemm2(const float* __restrict__ hid,
                                               const float* __restrict__ W2,
                                               float* __restrict__ h2) {
    int n = blockIdx.x * 256 + threadIdx.x;
    if (n >= NN) return;
    const float* p = hid + (size_t)n * HIDF;
    float acc[OUTF];
#pragma unroll
    for (int f = 0; f < OUTF; ++f) acc[f] = 0.f;
#pragma unroll 4
    for (int k = 0; k < HIDF; ++k) {
        float hv = p[k];
#pragma unroll
        for (int f = 0; f < OUTF; ++f)
            acc[f] = fmaf(hv, W2[k * OUTF + f], acc[f]);
    }
#pragma unroll
    for (int f = 0; f < OUTF; ++f)
        h2[(size_t)n * OUTF + f] = acc[f];
}

// --------------------------- layer2 aggregate + bias + log_softmax ---------
__global__ __launch_bounds__(256) void k_out2(const int* __restrict__ rs,
                                              const int* __restrict__ csr,
                                              const float* __restrict__ dinv,
                                              const float* __restrict__ h2,
                                              const float* __restrict__ b2,
                                              float* __restrict__ out) {
    int t = blockIdx.x * 256 + threadIdx.x;
    int n = t >> 4;
    int f = t & 15;
    if (n >= NN) return;
    int row = rs[n], end = rs[n + 1];
    float dn = dinv[n];
    float acc = dn * h2[n * OUTF + f];               // self-loop

    int j = row;
    for (; j + 2 <= end; j += 2) {
        int s0 = csr[j], s1 = csr[j + 1];
        acc = fmaf(h2[s0 * OUTF + f], dinv[s0], acc);
        acc = fmaf(h2[s1 * OUTF + f], dinv[s1], acc);
    }
    for (; j < end; ++j) {
        int s = csr[j];
        acc = fmaf(h2[s * OUTF + f], dinv[s], acc);
    }
    float v = fmaf(dn, acc, b2[f]);

    float m = v;
#pragma unroll
    for (int mask = 1; mask < 16; mask <<= 1)
        m = fmaxf(m, __shfl_xor(m, mask, 16));
    float ex = __expf(v - m);
    float s  = ex;
#pragma unroll
    for (int mask = 1; mask < 16; mask <<= 1)
        s += __shfl_xor(s, mask, 16);
    out[(size_t)n * OUTF + f] = v - (m + __logf(s));
}

// ----------------------------------------------------------------- launch --
extern "C" void kernel_launch(void* const* d_in, const int* in_sizes, int n_in,
                              void* d_out, int out_size, void* d_ws, size_t ws_size,
                              hipStream_t stream) {
    const float* x  = (const float*)d_in[0];
    const int*   ei = (const int*)d_in[1];    // [2][NE], delivered as int32
    const float* W1 = (const float*)d_in[2];
    const float* b1 = (const float*)d_in[3];
    const float* W2 = (const float*)d_in[4];
    const float* b2 = (const float*)d_in[5];
    float*       out = (float*)d_out;

    char*  ws = (char*)d_ws;
    size_t o  = 0;
    auto alloc = [&](size_t bytes) {
        void* p = ws + o;
        o = (o + bytes + 1023) & ~(size_t)1023;
        return p;
    };
    int*   cnt    = (int*)  alloc((size_t)NN * 4);
    int*   rs     = (int*)  alloc((size_t)(NN + 1) * 4);
    int*   cursor = (int*)  alloc((size_t)NN * 4);
    int*   bsum   = (int*)  alloc((size_t)NB_SCAN * 4);
    int*   boff   = (int*)  alloc((size_t)NB_SCAN * 4);
    int*   csr    = (int*)  alloc((size_t)NE * 4);
    float* dinv   = (float*)alloc((size_t)NN * 4);
    float* h1p    = (float*)alloc((size_t)NN * HIDF * 4);
    float* hid    = (float*)alloc((size_t)NN * HIDF * 4);
    float* h2     = (float*)alloc((size_t)NN * OUTF * 4);
    if (o > ws_size) return;   // insufficient scratch -> visible failure

    const int* esrc = ei;
    const int* edst = ei + NE;

    hipMemsetAsync(cnt, 0, (size_t)NN * 4, stream);

    k_deg_count<<<(NE + 255) / 256, 256, 0, stream>>>(edst, cnt);
    k_dinv     <<<(NN + 255) / 256, 256, 0, stream>>>(cnt, dinv);
    k_scan1    <<<NB_SCAN, 256, 0, stream>>>(cnt, rs, bsum);
    k_scan2    <<<1, 128, 0, stream>>>(bsum, boff);
    k_scan3    <<<(NN + 255) / 256, 256, 0, stream>>>(rs, boff, cursor);
    k_fill     <<<(NE + 255) / 256, 256, 0, stream>>>(esrc, edst, cursor, csr);

    k_gemm1    <<<(NN + MT - 1) / MT, 256, 0, stream>>>(x, W1, h1p);   // 782 blocks
    k_hid      <<<(NN * 64 + 255) / 256, 256, 0, stream>>>(rs, csr, dinv, h1p, b1, hid);
    k_gemm2    <<<(NN + 255) / 256, 256, 0, stream>>>(hid, W2, h2);
    k_out2     <<<(NN * OUTF + 255) / 256, 256, 0, stream>>>(rs, csr, dinv, h2, b2, out);
}